// Round 1
// baseline (312.771 us; speedup 1.0000x reference)
//
#include <hip/hip_runtime.h>

typedef unsigned short u16;
typedef unsigned int u32;
typedef u16 u16x8 __attribute__((ext_vector_type(8)));
typedef u16 u16x4 __attribute__((ext_vector_type(4)));
typedef __bf16 bf16x8 __attribute__((ext_vector_type(8)));
typedef float f32x4 __attribute__((ext_vector_type(4)));

// ---------- helpers ----------
__device__ __forceinline__ u16 f2bf(float f) {
    u32 u = __builtin_bit_cast(u32, f);
    u32 r = (u + 0x7fffu + ((u >> 16) & 1u)) >> 16;
    return (u16)r;
}
__device__ __forceinline__ float bf2f(u16 s) {
    u32 u = ((u32)s) << 16;
    return __builtin_bit_cast(float, u);
}
__device__ __forceinline__ void async16(const u16* g, u16* lds_base) {
    // HW writes lds_base + lane*16B; lds_base must be wave-uniform.
    __builtin_amdgcn_global_load_lds(
        (const __attribute__((address_space(1))) void*)g,
        (__attribute__((address_space(3))) void*)lds_base, 16, 0, 0);
}
__device__ __forceinline__ void storeC(float* p, float v) { *p = v; }
__device__ __forceinline__ void storeC(u16* p, float v)   { *p = f2bf(v); }

// ---------- fp32 -> bf16 convert (8 elems/thread) ----------
__global__ void cvt_f32_bf16(const float* __restrict__ in, u16* __restrict__ out, long n) {
    long idx = ((long)blockIdx.x * blockDim.x + threadIdx.x) * 8;
    if (idx >= n) return;
    float4 a = *(const float4*)(in + idx);
    float4 b = *(const float4*)(in + idx + 4);
    u16x8 o;
    o[0] = f2bf(a.x); o[1] = f2bf(a.y); o[2] = f2bf(a.z); o[3] = f2bf(a.w);
    o[4] = f2bf(b.x); o[5] = f2bf(b.y); o[6] = f2bf(b.z); o[7] = f2bf(b.w);
    *(u16x8*)(out + idx) = o;
}

// ---------- transpose+convert Wq/Wk/Wv -> WqkvT [3072][1024] bf16 ----------
// WT[z*1024 + n][k] = W_z[k][n]
__global__ void transpose_cvt(const float* __restrict__ W0, const float* __restrict__ W1,
                              const float* __restrict__ W2, u16* __restrict__ WT) {
    __shared__ float tile[32][33];
    const float* W = (blockIdx.z == 0) ? W0 : (blockIdx.z == 1) ? W1 : W2;
    int n0 = blockIdx.x * 32, k0 = blockIdx.y * 32;
    int tx = threadIdx.x, ty = threadIdx.y;
#pragma unroll
    for (int r = 0; r < 4; ++r)
        tile[ty + 8 * r][tx] = W[(size_t)(k0 + ty + 8 * r) * 1024 + n0 + tx];
    __syncthreads();
#pragma unroll
    for (int r = 0; r < 4; ++r) {
        int n = n0 + ty + 8 * r;
        WT[((size_t)blockIdx.z * 1024 + n) * 1024 + k0 + tx] = f2bf(tile[tx][ty + 8 * r]);
    }
}

// ---------- 128x128 tile bf16 MFMA GEMM: C[m][n] = sum_k A[m][k]*Bt[n][k] ----------
template <typename OutT>
__global__ __launch_bounds__(256, 2) void gemm_bt(
    const u16* __restrict__ A, int lda,
    const u16* __restrict__ Bt, int ldb,
    OutT* __restrict__ C, int ldc, int K) {
    __shared__ u16 As[128 * 32];
    __shared__ u16 Bs[128 * 32];
    const int tid = threadIdx.x;
    const int w = tid >> 6, lane = tid & 63;
    const int wr = w >> 1, wc = w & 1;
    const size_t mBase = (size_t)blockIdx.y * 128;
    const size_t nBase = (size_t)blockIdx.x * 128;

    f32x4 acc[4][4] = {};

    const int sr = lane >> 2;          // 0..15
    const int sc = (lane & 3) * 8;     // 0,8,16,24

    for (int k0 = 0; k0 < K; k0 += 32) {
        __syncthreads();
#pragma unroll
        for (int j = 0; j < 2; ++j) {
            int row = w * 32 + j * 16;
            async16(A + (mBase + row + sr) * lda + k0 + sc, &As[row * 32]);
            async16(Bt + (nBase + row + sr) * ldb + k0 + sc, &Bs[row * 32]);
        }
        __syncthreads();
        bf16x8 a[4], b[4];
#pragma unroll
        for (int m = 0; m < 4; ++m)
            a[m] = *(const bf16x8*)&As[(wr * 64 + m * 16 + (lane & 15)) * 32 + (lane >> 4) * 8];
#pragma unroll
        for (int n = 0; n < 4; ++n)
            b[n] = *(const bf16x8*)&Bs[(wc * 64 + n * 16 + (lane & 15)) * 32 + (lane >> 4) * 8];
#pragma unroll
        for (int m = 0; m < 4; ++m)
#pragma unroll
            for (int n = 0; n < 4; ++n)
                acc[m][n] = __builtin_amdgcn_mfma_f32_16x16x32_bf16(a[m], b[n], acc[m][n], 0, 0, 0);
    }

    const int rb = (lane >> 4) * 4;
    const int cx = lane & 15;
#pragma unroll
    for (int m = 0; m < 4; ++m) {
#pragma unroll
        for (int n = 0; n < 4; ++n) {
            size_t col = nBase + wc * 64 + n * 16 + cx;
#pragma unroll
            for (int r = 0; r < 4; ++r) {
                size_t row = mBase + wr * 64 + m * 16 + rb + r;
                storeC(&C[row * ldc + col], acc[m][n][r]);
            }
        }
    }
}

// ---------- kv partials: P[c][b][h][i][j] = sum_{s in chunk} K[s][i]*V[s][j] ----------
__global__ void kv_partial(const u16* __restrict__ Y, float* __restrict__ P) {
    int c = blockIdx.x, h = blockIdx.y, b = blockIdx.z;
    __shared__ u16 Ks[64 * 64];
    __shared__ u16 Vs[64 * 64];
    int t = threadIdx.x;
    int i = t >> 2, j0 = (t & 3) * 16;
    float acc[16] = {};
    int rowBase = b * 4096 + c * 512;
    int r = t >> 2, cc = (t & 3) * 16;
    for (int st = 0; st < 8; ++st) {
        __syncthreads();
        const u16* gK = Y + (size_t)(rowBase + st * 64 + r) * 3072 + 1024 + h * 64 + cc;
        const u16* gV = gK + 1024;
        *(u16x8*)&Ks[r * 64 + cc]     = *(const u16x8*)gK;
        *(u16x8*)&Ks[r * 64 + cc + 8] = *(const u16x8*)(gK + 8);
        *(u16x8*)&Vs[r * 64 + cc]     = *(const u16x8*)gV;
        *(u16x8*)&Vs[r * 64 + cc + 8] = *(const u16x8*)(gV + 8);
        __syncthreads();
        for (int s = 0; s < 64; ++s) {
            float kv = bf2f(Ks[s * 64 + i]);
            const u16* vr = &Vs[s * 64 + j0];
            u16x4 v0 = *(const u16x4*)(vr);
            u16x4 v1 = *(const u16x4*)(vr + 4);
            u16x4 v2 = *(const u16x4*)(vr + 8);
            u16x4 v3 = *(const u16x4*)(vr + 12);
#pragma unroll
            for (int q = 0; q < 4; ++q) {
                acc[q]      += kv * bf2f(v0[q]);
                acc[4 + q]  += kv * bf2f(v1[q]);
                acc[8 + q]  += kv * bf2f(v2[q]);
                acc[12 + q] += kv * bf2f(v3[q]);
            }
        }
    }
    float* p = P + (((size_t)c * 4 + b) * 16 + h) * 4096 + i * 64 + j0;
#pragma unroll
    for (int q = 0; q < 4; ++q)
        *(float4*)(p + 4 * q) = make_float4(acc[4 * q], acc[4 * q + 1], acc[4 * q + 2], acc[4 * q + 3]);
}

// ---------- kv reduce over 8 chunks ----------
__global__ void kv_reduce(const float* __restrict__ P, float* __restrict__ kvb) {
    int bh = blockIdx.x;  // b*16+h
    int t = threadIdx.x;
    for (int idx = t; idx < 4096; idx += 256) {
        float s = 0.f;
#pragma unroll
        for (int c = 0; c < 8; ++c) s += P[((size_t)(c * 64 + bh)) * 4096 + idx];
        kvb[(size_t)bh * 4096 + idx] = s;
    }
}

// ---------- out = scale * Q @ kv, written into K-region of Y ----------
__global__ void attn_out(const u16* __restrict__ Y, const float* __restrict__ kvb,
                         u16* __restrict__ Yout) {
    int h = blockIdx.y;
    int m0 = blockIdx.x * 64;     // global row
    int b = m0 >> 12;
    __shared__ float kvs[4096];
    __shared__ u16 Qs[64 * 64];
    int t = threadIdx.x;
    {
        const float4* src = (const float4*)(kvb + (((size_t)b * 16 + h) << 12));
        float4* dst = (float4*)kvs;
#pragma unroll
        for (int q = 0; q < 4; ++q) dst[t + 256 * q] = src[t + 256 * q];
        int r = t >> 2, c = (t & 3) * 16;
        const u16* g = Y + (size_t)(m0 + r) * 3072 + h * 64 + c;
        *(u16x8*)&Qs[r * 64 + c]     = *(const u16x8*)g;
        *(u16x8*)&Qs[r * 64 + c + 8] = *(const u16x8*)(g + 8);
    }
    __syncthreads();
    int r = t >> 2, j0 = (t & 3) * 16;
    float acc[16] = {};
    for (int i = 0; i < 64; ++i) {
        float q = bf2f(Qs[r * 64 + i]);
        const float* kr = &kvs[i * 64 + j0];
#pragma unroll
        for (int jj = 0; jj < 16; ++jj) acc[jj] += q * kr[jj];
    }
    u16x8 o0, o1;
#pragma unroll
    for (int jj = 0; jj < 8; ++jj) {
        o0[jj] = f2bf(acc[jj] * 0.125f);
        o1[jj] = f2bf(acc[8 + jj] * 0.125f);
    }
    u16* gw = Yout + (size_t)(m0 + r) * 3072 + 1024 + h * 64 + j0;
    *(u16x8*)gw       = o0;
    *(u16x8*)(gw + 8) = o1;
}

extern "C" void kernel_launch(void* const* d_in, const int* in_sizes, int n_in,
                              void* d_out, int out_size, void* d_ws, size_t ws_size,
                              hipStream_t stream) {
    const float* x  = (const float*)d_in[0];
    const float* Wq = (const float*)d_in[1];
    const float* Wk = (const float*)d_in[2];
    const float* Wv = (const float*)d_in[3];
    const float* Wo = (const float*)d_in[4];
    float* out = (float*)d_out;
    char* ws = (char*)d_ws;

    // workspace layout (bytes)
    u16*   Y     = (u16*)(ws);                    // [16384][3072] bf16   96 MB
    u16*   xb    = (u16*)(ws + 100663296);        // [16384][1024] bf16   32 MB
    u16*   WqkvT = (u16*)(ws + 134217728);        // [3072][1024]  bf16    6 MB
    u16*   Wob   = (u16*)(ws + 140509184);        // [1024][1024]  bf16    2 MB
    float* P     = (float*)(ws + 142606336);      // [8][4][16][64][64]    8 MB
    float* kvb   = (float*)(ws + 150994944);      // [4][16][64][64]       1 MB

    cvt_f32_bf16<<<8192, 256, 0, stream>>>(x, xb, 16777216L);
    cvt_f32_bf16<<<512, 256, 0, stream>>>(Wo, Wob, 1048576L);
    transpose_cvt<<<dim3(32, 32, 3), dim3(32, 8), 0, stream>>>(Wq, Wk, Wv, WqkvT);

    // Y = [Q|K|V] = xb @ [Wq|Wk|Wv]
    gemm_bt<u16><<<dim3(24, 128), 256, 0, stream>>>(xb, 1024, WqkvT, 1024, Y, 3072, 1024);

    kv_partial<<<dim3(8, 16, 4), 256, 0, stream>>>(Y, P);
    kv_reduce<<<64, 256, 0, stream>>>(P, kvb);

    // out (scaled) -> K-region of Y (cols 1024..2047)
    attn_out<<<dim3(256, 16), 256, 0, stream>>>(Y, kvb, Y);

    // final = out @ Wo^T
    gemm_bt<float><<<dim3(8, 128), 256, 0, stream>>>(Y + 1024, 3072, Wob, 1024, out, 1024, 1024);
}